// Round 8
// baseline (46.382 us; speedup 1.0000x reference)
//
#include <hip/hip_runtime.h>

#define OBS_DIM 99
#define CH      128
#define HID     256
#define BPB     8     // batch items per block

__device__ __forceinline__ float dot4(float4 a, float4 b) {
    return fmaf(a.x, b.x, fmaf(a.y, b.y, fmaf(a.z, b.z, a.w * b.w)));
}

__global__ __launch_bounds__(256, 4) void gnn_fused(
    const float* __restrict__ obs,      // (B, 99)
    const float* __restrict__ W_fgn,    // (4, 512)
    const float* __restrict__ b_fgn,    // (512,)
    const float* __restrict__ W_root,   // (4, 128)
    const float* __restrict__ b_conv,   // (128,)
    const float* __restrict__ attn_k,   // (128,)
    const float* __restrict__ W_dense,  // (128, 256)
    const float* __restrict__ b_dense,  // (256,)
    float* __restrict__ out)            // (B, 256)
{
    __shared__ __align__(16) float lobs[BPB][96];    // X(16) | A(16) | E(64)
    __shared__ __align__(16) float lm[BPB][80];      // M[t*16+e*4+f](64) | AX[t*4+f](16)
    __shared__ __align__(16) float lpool[BPB][132];  // fp32 pooled
    __shared__ float lwp[2][4][4];                   // double-buffered logit partials

    const int tid  = threadIdx.x;
    const int b0   = blockIdx.x * BPB;
    const int lane = tid & 63;
    const int wid  = tid >> 6;

    // ---- stage observations (8 rows x 96 cols) ----
    for (int i = tid; i < BPB * 96; i += 256) {
        const int bi = i / 96, col = i - bi * 96;
        lobs[bi][col] = obs[(size_t)(b0 + bi) * OBS_DIM + 3 + col];
    }

    // ---- per-channel weights (c = tid & 127), kept register-resident ----
    const int c = tid & 127;
    float4 Wf4[4];
    #pragma unroll
    for (int e = 0; e < 4; ++e)
        Wf4[e] = *reinterpret_cast<const float4*>(&W_fgn[e * 512 + c * 4]);
    const float4 bf4 = *reinterpret_cast<const float4*>(&b_fgn[c * 4]);
    const float4 Wr  = make_float4(W_root[c], W_root[CH + c],
                                   W_root[2 * CH + c], W_root[3 * CH + c]);
    const float bcv = b_conv[c];
    const float ak  = attn_k[c];

    __syncthreads();

    // ---- step A: per-item shared tensors M[t,e,f], AX[t,f] ----
    if (tid < BPB * 16) {
        const int bi = tid >> 4;          // 0..7
        const int t  = (tid >> 2) & 3;
        const int e  = tid & 3;
        float4 m = make_float4(0.f, 0.f, 0.f, 0.f);
        #pragma unroll
        for (int s = 0; s < 4; ++s) {
            const float ae = lobs[bi][16 + t * 4 + s] * lobs[bi][32 + (t * 4 + s) * 4 + e];
            const float4 X = *reinterpret_cast<const float4*>(&lobs[bi][s * 4]);
            m.x = fmaf(ae, X.x, m.x);
            m.y = fmaf(ae, X.y, m.y);
            m.z = fmaf(ae, X.z, m.z);
            m.w = fmaf(ae, X.w, m.w);
        }
        *reinterpret_cast<float4*>(&lm[bi][t * 16 + e * 4]) = m;
    }
    if (tid < BPB * 4) {
        const int bi = tid >> 2, t = tid & 3;
        float4 ax = make_float4(0.f, 0.f, 0.f, 0.f);
        #pragma unroll
        for (int s = 0; s < 4; ++s) {
            const float a = lobs[bi][16 + t * 4 + s];
            const float4 X = *reinterpret_cast<const float4*>(&lobs[bi][s * 4]);
            ax.x = fmaf(a, X.x, ax.x);
            ax.y = fmaf(a, X.y, ax.y);
            ax.z = fmaf(a, X.z, ax.z);
            ax.w = fmaf(a, X.w, ax.w);
        }
        *reinterpret_cast<float4*>(&lm[bi][64 + t * 4]) = ax;
    }
    __syncthreads();

    // ---- phase 1: per-channel conv + attention pooling ----
    const int half = tid >> 7;
    #pragma unroll 1
    for (int p = 0; p < BPB / 2; ++p) {
        const int bi = p * 2 + half;

        float xc[4], pt[4];
        #pragma unroll
        for (int t = 0; t < 4; ++t) {
            float m = bcv + dot4(bf4, *reinterpret_cast<const float4*>(&lm[bi][64 + t * 4]));
            #pragma unroll
            for (int e = 0; e < 4; ++e)
                m += dot4(Wf4[e], *reinterpret_cast<const float4*>(&lm[bi][t * 16 + e * 4]));
            m += dot4(*reinterpret_cast<const float4*>(&lobs[bi][t * 4]), Wr);
            xc[t] = fmaxf(m, 0.f);
            pt[t] = xc[t] * ak;
        }

        #pragma unroll
        for (int st = 1; st < 64; st <<= 1) {
            #pragma unroll
            for (int t = 0; t < 4; ++t) pt[t] += __shfl_xor(pt[t], st, 64);
        }
        if (lane == 0) {
            #pragma unroll
            for (int t = 0; t < 4; ++t) lwp[p & 1][wid][t] = pt[t];
        }
        __syncthreads();

        float l[4];
        #pragma unroll
        for (int t = 0; t < 4; ++t)
            l[t] = lwp[p & 1][half * 2][t] + lwp[p & 1][half * 2 + 1][t];
        const float mx = fmaxf(fmaxf(l[0], l[1]), fmaxf(l[2], l[3]));
        const float e0 = __expf(l[0] - mx), e1 = __expf(l[1] - mx);
        const float e2 = __expf(l[2] - mx), e3 = __expf(l[3] - mx);
        const float inv = 1.f / (e0 + e1 + e2 + e3);
        lpool[bi][c] = (e0 * xc[0] + e1 * xc[1] + e2 * xc[2] + e3 * xc[3]) * inv;
        // lwp double-buffered: no trailing barrier needed
    }
    __syncthreads();

    // ---- phase 2: pooled(8x128) @ W_dense(128x256), fp32 VALU ----
    // thread -> rows {bq*2, bq*2+1}, cols hq*4..hq*4+3; 1024 FMA/thread.
    const int hq = tid & 63;
    const int bq = tid >> 6;
    float acc[2][4];
    #pragma unroll
    for (int j = 0; j < 2; ++j)
        #pragma unroll
        for (int i = 0; i < 4; ++i) acc[j][i] = 0.f;

    #pragma unroll 4
    for (int cc = 0; cc < CH; cc += 4) {
        float4 pv[2], wr[4];
        #pragma unroll
        for (int j = 0; j < 2; ++j)
            pv[j] = *reinterpret_cast<const float4*>(&lpool[bq * 2 + j][cc]);
        #pragma unroll
        for (int k = 0; k < 4; ++k)
            wr[k] = *reinterpret_cast<const float4*>(&W_dense[(size_t)(cc + k) * HID + hq * 4]);
        #pragma unroll
        for (int j = 0; j < 2; ++j) {
            const float pj[4] = {pv[j].x, pv[j].y, pv[j].z, pv[j].w};
            #pragma unroll
            for (int k = 0; k < 4; ++k) {
                acc[j][0] = fmaf(pj[k], wr[k].x, acc[j][0]);
                acc[j][1] = fmaf(pj[k], wr[k].y, acc[j][1]);
                acc[j][2] = fmaf(pj[k], wr[k].z, acc[j][2]);
                acc[j][3] = fmaf(pj[k], wr[k].w, acc[j][3]);
            }
        }
    }

    const float4 bd = *reinterpret_cast<const float4*>(&b_dense[hq * 4]);
    #pragma unroll
    for (int j = 0; j < 2; ++j) {
        float4 o;
        o.x = tanhf(acc[j][0] + bd.x);
        o.y = tanhf(acc[j][1] + bd.y);
        o.z = tanhf(acc[j][2] + bd.z);
        o.w = tanhf(acc[j][3] + bd.w);
        *reinterpret_cast<float4*>(&out[(size_t)(b0 + bq * 2 + j) * HID + hq * 4]) = o;
    }
}

extern "C" void kernel_launch(void* const* d_in, const int* in_sizes, int n_in,
                              void* d_out, int out_size, void* d_ws, size_t ws_size,
                              hipStream_t stream) {
    const float* obs     = (const float*)d_in[0];
    const float* W_fgn   = (const float*)d_in[1];
    const float* b_fgn   = (const float*)d_in[2];
    const float* W_root  = (const float*)d_in[3];
    const float* b_conv  = (const float*)d_in[4];
    const float* attn_k  = (const float*)d_in[5];
    const float* W_dense = (const float*)d_in[6];
    const float* b_dense = (const float*)d_in[7];
    float* out = (float*)d_out;

    const int Bn = in_sizes[0] / OBS_DIM;     // 16384
    gnn_fused<<<Bn / BPB, 256, 0, stream>>>(obs, W_fgn, b_fgn, W_root, b_conv,
                                            attn_k, W_dense, b_dense, out);
}

// Round 9
// 37.102 us; speedup vs baseline: 1.2501x; 1.2501x over previous
//
#include <hip/hip_runtime.h>

#define OBS_DIM 99
#define CH      128
#define HID     256
#define BPB     16

__device__ __forceinline__ float dot4(float4 a, float4 b) {
    return fmaf(a.x, b.x, fmaf(a.y, b.y, fmaf(a.z, b.z, a.w * b.w)));
}

__device__ __forceinline__ float ftanh(float x) {
    // tanh(x) = 1 - 2/(e^{2x}+1); rcp rel-err ~1e-5, saturates correctly at +-inf
    const float t = __expf(2.f * x);
    return 1.f - 2.f * __builtin_amdgcn_rcpf(t + 1.f);
}

__global__ __launch_bounds__(256, 4) void gnn_fused(
    const float* __restrict__ obs,      // (B, 99)
    const float* __restrict__ W_fgn,    // (4, 512)
    const float* __restrict__ b_fgn,    // (512,)
    const float* __restrict__ W_root,   // (4, 128)
    const float* __restrict__ b_conv,   // (128,)
    const float* __restrict__ attn_k,   // (128,)
    const float* __restrict__ W_dense,  // (128, 256)
    const float* __restrict__ b_dense,  // (256,)
    float* __restrict__ out)            // (B, 256)
{
    __shared__ __align__(16) float lobs[BPB][96];    // X(16) | A(16) | E(64)
    __shared__ __align__(16) float lm[BPB][80];      // M[t*16+e*4+f](64) | AX[t*4+f](16)
    __shared__ __align__(16) float lpool[BPB][132];  // fp32 pooled

    const int tid  = threadIdx.x;
    const int b0   = blockIdx.x * BPB;
    const int lane = tid & 63;
    const int w    = tid >> 6;

    // ---- stage observations (16 rows x 96 cols) ----
    for (int i = tid; i < BPB * 96; i += 256) {
        const int bi = i / 96, col = i - bi * 96;
        lobs[bi][col] = obs[(size_t)(b0 + bi) * OBS_DIM + 3 + col];
    }

    // ---- per-lane weights for channels c0 = lane, c1 = lane + 64 ----
    float4 Wf4[2][4], bf4[2], Wr[2];
    float  bcv[2], ak[2];
    #pragma unroll
    for (int ch = 0; ch < 2; ++ch) {
        const int c = lane + ch * 64;
        #pragma unroll
        for (int e = 0; e < 4; ++e)
            Wf4[ch][e] = *reinterpret_cast<const float4*>(&W_fgn[e * 512 + c * 4]);
        bf4[ch] = *reinterpret_cast<const float4*>(&b_fgn[c * 4]);
        Wr[ch]  = make_float4(W_root[c], W_root[CH + c], W_root[2 * CH + c], W_root[3 * CH + c]);
        bcv[ch] = b_conv[c];
        ak[ch]  = attn_k[c];
    }

    __syncthreads();

    // ---- step A: per-item shared tensors M[t,e,f], AX[t,f] ----
    // M[t,e,f] = sum_s A[t,s]*E[t,s,e]*X[s,f];  AX[t,f] = sum_s A[t,s]*X[s,f]
    {
        const int bi = tid >> 4;          // 0..15  (16 items x 16 (t,e) tasks = 256)
        const int t  = (tid >> 2) & 3;
        const int e  = tid & 3;
        float4 m = make_float4(0.f, 0.f, 0.f, 0.f);
        #pragma unroll
        for (int s = 0; s < 4; ++s) {
            const float ae = lobs[bi][16 + t * 4 + s] * lobs[bi][32 + (t * 4 + s) * 4 + e];
            const float4 X = *reinterpret_cast<const float4*>(&lobs[bi][s * 4]);
            m.x = fmaf(ae, X.x, m.x);
            m.y = fmaf(ae, X.y, m.y);
            m.z = fmaf(ae, X.z, m.z);
            m.w = fmaf(ae, X.w, m.w);
        }
        *reinterpret_cast<float4*>(&lm[bi][t * 16 + e * 4]) = m;
    }
    if (tid < BPB * 4) {
        const int bi = tid >> 2, t = tid & 3;
        float4 ax = make_float4(0.f, 0.f, 0.f, 0.f);
        #pragma unroll
        for (int s = 0; s < 4; ++s) {
            const float a = lobs[bi][16 + t * 4 + s];
            const float4 X = *reinterpret_cast<const float4*>(&lobs[bi][s * 4]);
            ax.x = fmaf(a, X.x, ax.x);
            ax.y = fmaf(a, X.y, ax.y);
            ax.z = fmaf(a, X.z, ax.z);
            ax.w = fmaf(a, X.w, ax.w);
        }
        *reinterpret_cast<float4*>(&lm[bi][64 + t * 4]) = ax;
    }
    __syncthreads();

    // ---- phase 1: wave-private conv + attention pooling (no barriers) ----
    // wave w owns items {4w..4w+3}; lane owns channels {lane, lane+64}.
    #pragma unroll 1
    for (int p = 0; p < 4; ++p) {
        const int bi = w * 4 + p;

        float xc[2][4], pt[4];
        #pragma unroll
        for (int t = 0; t < 4; ++t) {
            const float4 ax = *reinterpret_cast<const float4*>(&lm[bi][64 + t * 4]);
            const float4 m0 = *reinterpret_cast<const float4*>(&lm[bi][t * 16 + 0]);
            const float4 m1 = *reinterpret_cast<const float4*>(&lm[bi][t * 16 + 4]);
            const float4 m2 = *reinterpret_cast<const float4*>(&lm[bi][t * 16 + 8]);
            const float4 m3 = *reinterpret_cast<const float4*>(&lm[bi][t * 16 + 12]);
            const float4 x4 = *reinterpret_cast<const float4*>(&lobs[bi][t * 4]);
            #pragma unroll
            for (int ch = 0; ch < 2; ++ch) {
                float v = bcv[ch] + dot4(bf4[ch], ax)
                        + dot4(Wf4[ch][0], m0) + dot4(Wf4[ch][1], m1)
                        + dot4(Wf4[ch][2], m2) + dot4(Wf4[ch][3], m3)
                        + dot4(x4, Wr[ch]);
                xc[ch][t] = fmaxf(v, 0.f);
            }
            pt[t] = fmaf(xc[0][t], ak[0], xc[1][t] * ak[1]);
        }

        // full 128-channel logit sum: one 64-lane butterfly
        #pragma unroll
        for (int st = 1; st < 64; st <<= 1) {
            #pragma unroll
            for (int t = 0; t < 4; ++t) pt[t] += __shfl_xor(pt[t], st, 64);
        }

        const float mx = fmaxf(fmaxf(pt[0], pt[1]), fmaxf(pt[2], pt[3]));
        const float e0 = __expf(pt[0] - mx), e1 = __expf(pt[1] - mx);
        const float e2 = __expf(pt[2] - mx), e3 = __expf(pt[3] - mx);
        const float inv = 1.f / (e0 + e1 + e2 + e3);
        lpool[bi][lane]      = (e0 * xc[0][0] + e1 * xc[0][1] + e2 * xc[0][2] + e3 * xc[0][3]) * inv;
        lpool[bi][lane + 64] = (e0 * xc[1][0] + e1 * xc[1][1] + e2 * xc[1][2] + e3 * xc[1][3]) * inv;
    }
    __syncthreads();

    // ---- phase 2: pooled(16x128) @ W_dense(128x256), wave-sliced columns ----
    // wave w covers cols [64w, 64w+64): per-block W_dense L2 footprint = 128 KB.
    const int col0 = w * 64 + (lane & 15) * 4;
    const int rb   = (lane >> 4) * 4;
    float acc[4][4];
    #pragma unroll
    for (int j = 0; j < 4; ++j)
        #pragma unroll
        for (int i = 0; i < 4; ++i) acc[j][i] = 0.f;

    #pragma unroll 4
    for (int cc = 0; cc < CH; cc += 4) {
        float4 pv[4], wr[4];
        #pragma unroll
        for (int j = 0; j < 4; ++j)
            pv[j] = *reinterpret_cast<const float4*>(&lpool[rb + j][cc]);
        #pragma unroll
        for (int k = 0; k < 4; ++k)
            wr[k] = *reinterpret_cast<const float4*>(&W_dense[(size_t)(cc + k) * HID + col0]);
        #pragma unroll
        for (int j = 0; j < 4; ++j) {
            const float pj[4] = {pv[j].x, pv[j].y, pv[j].z, pv[j].w};
            #pragma unroll
            for (int k = 0; k < 4; ++k) {
                acc[j][0] = fmaf(pj[k], wr[k].x, acc[j][0]);
                acc[j][1] = fmaf(pj[k], wr[k].y, acc[j][1]);
                acc[j][2] = fmaf(pj[k], wr[k].z, acc[j][2]);
                acc[j][3] = fmaf(pj[k], wr[k].w, acc[j][3]);
            }
        }
    }

    const float4 bd = *reinterpret_cast<const float4*>(&b_dense[col0]);
    #pragma unroll
    for (int j = 0; j < 4; ++j) {
        float4 o;
        o.x = ftanh(acc[j][0] + bd.x);
        o.y = ftanh(acc[j][1] + bd.y);
        o.z = ftanh(acc[j][2] + bd.z);
        o.w = ftanh(acc[j][3] + bd.w);
        *reinterpret_cast<float4*>(&out[(size_t)(b0 + rb + j) * HID + col0]) = o;
    }
}

extern "C" void kernel_launch(void* const* d_in, const int* in_sizes, int n_in,
                              void* d_out, int out_size, void* d_ws, size_t ws_size,
                              hipStream_t stream) {
    const float* obs     = (const float*)d_in[0];
    const float* W_fgn   = (const float*)d_in[1];
    const float* b_fgn   = (const float*)d_in[2];
    const float* W_root  = (const float*)d_in[3];
    const float* b_conv  = (const float*)d_in[4];
    const float* attn_k  = (const float*)d_in[5];
    const float* W_dense = (const float*)d_in[6];
    const float* b_dense = (const float*)d_in[7];
    float* out = (float*)d_out;

    const int Bn = in_sizes[0] / OBS_DIM;     // 16384
    gnn_fused<<<Bn / BPB, 256, 0, stream>>>(obs, W_fgn, b_fgn, W_root, b_conv,
                                            attn_k, W_dense, b_dense, out);
}